// Round 12
// baseline (38.152 us; speedup 1.0000x reference)
//
#include <hip/hip_runtime.h>
#include <math.h>

// Problem constants
#define BB 128
#define MM 50
#define CC 43
#define IMGF 416.0f

// Per-scale geometry:
//  s=0: W=52 A=2704 stride=8  chunks/b=11  blocks [0,1408)
//  s=1: W=26 A=676  stride=16 chunks/b=3   blocks [1408,1792)
//  s=2: W=13 A=169  stride=32 chunks/b=1   blocks [1792,1920)
#define NBLK0 1408
#define NBLK01 1792
#define NBLK_TOTAL 1920

// fast, algebraically-equivalent focal:
// bce = max(x,0) - x*t + log1p(e^-|x|);  pt = exp(-bce) == (t ? sig(x) : 1-sig(x))
__device__ __forceinline__ float focal_fast(float x, bool t) {
    float e = __expf(-fabsf(x));          // v_exp
    float denom = 1.0f + e;
    float l = __logf(denom);              // v_log : log(1+e) == log1p(e^-|x|)
    float bce = fmaxf(x, 0.0f) - (t ? x : 0.0f) + l;
    float r = __builtin_amdgcn_rcpf(denom);   // v_rcp
    float sig = (x >= 0.0f) ? r : e * r;
    float pt = t ? sig : 1.0f - sig;
    float om = 1.0f - pt;
    return 0.25f * om * om * bce;
}

__device__ __forceinline__ float bce_fast(float x, bool t) {
    float e = __expf(-fabsf(x));
    float l = __logf(1.0f + e);
    return fmaxf(x, 0.0f) - (t ? x : 0.0f) + l;
}

// SESSION RULES: (1) no agent-scope ordered atomics anywhere (R8/R9 A/B:
// 49->96us); final reduce stays a separate kernel. (2) R11: register-batching
// the 43 gathers regressed (occupancy loss, no MLP gain) — don't.
// R12 delta: DENSE cls streaming. Wave w sweeps channels c=w+4*cb over the
// block's full 256-anchor window with one float4 load per channel (1KB/wave
// dense, unconditional) instead of exec-mask-sparse per-fg-thread gathers.
// Per-anchor class masks published through LDS (thread's own slot overwrite).
__global__ __launch_bounds__(256) void v3_main(
    const float* __restrict__ cls0, const float* __restrict__ reg0, const float* __restrict__ obj0,
    const float* __restrict__ cls1, const float* __restrict__ reg1, const float* __restrict__ obj1,
    const float* __restrict__ cls2, const float* __restrict__ reg2, const float* __restrict__ obj2,
    const float* __restrict__ bboxes, const int* __restrict__ labels,
    float* __restrict__ partials)
{
    const int bid = blockIdx.x;
    int s, b, chunk;
    if (bid < NBLK0)       { s = 0; b = bid / 11; chunk = bid - 11 * b; }
    else if (bid < NBLK01) { int r = bid - NBLK0; s = 1; b = r / 3; chunk = r - 3 * b; }
    else                   { s = 2; b = bid - NBLK01; chunk = 0; }

    int W, A; float strd, inv_strd;
    const float *cls, *reg, *obj;
    if (s == 0)      { W = 52; A = 2704; strd = 8.f;  inv_strd = 0.125f;   cls = cls0; reg = reg0; obj = obj0; }
    else if (s == 1) { W = 26; A = 676;  strd = 16.f; inv_strd = 0.0625f;  cls = cls1; reg = reg1; obj = obj1; }
    else             { W = 13; A = 169;  strd = 32.f; inv_strd = 0.03125f; cls = cls2; reg = reg2; obj = obj2; }

    const int tid = threadIdx.x;
    const int lane = tid & 63, wid = tid >> 6;
    const int a_lo = chunk << 8;
    const int a_hi = min(a_lo + 255, A - 1);
    const int a = a_lo + tid;
    const bool active = (a < A);

    // ---- LDS: GT staging + per-cell masks (block-local) ----
    __shared__ int    s_lab[MM];
    __shared__ float4 s_boxv[MM];
    __shared__ alignas(16) unsigned s_glo[256];
    __shared__ alignas(16) unsigned s_ghi[256];

    // Phase 1a: zero cell masks; 50 lanes stage GT data + centers
    s_glo[tid] = 0u; s_ghi[tid] = 0u;
    int gx = -1, gy = -1, my_lab = -1;
    if (tid < MM) {
        my_lab = labels[b * MM + tid];
        float4 bb = ((const float4*)bboxes)[b * MM + tid];
        float4 pb = make_float4(bb.x * IMGF, bb.y * IMGF, bb.z * IMGF, bb.w * IMGF);
        s_boxv[tid] = pb;
        s_lab[tid] = min(max(my_lab, 0), CC - 1);
        float cx = (pb.x + pb.z) * 0.5f;
        float cy = (pb.y + pb.w) * 0.5f;
        gx = (int)(cx * inv_strd); gx = min(max(gx, 0), W - 1);
        gy = (int)(cy * inv_strd); gy = min(max(gy, 0), W - 1);
    }
    __syncthreads();

    // Phase 1b: idempotent scatter of GT bits into this block's cell window
    if (tid < MM && my_lab >= 0) {
        unsigned bit = 1u << (tid & 31);
        bool is_hi = (tid >= 32);
        #pragma unroll
        for (int dy = -1; dy <= 1; ++dy) {
            int yy = gy + dy;
            if ((unsigned)yy < (unsigned)W) {
                #pragma unroll
                for (int dx = -1; dx <= 1; ++dx) {
                    int xx = gx + dx;
                    if ((unsigned)xx < (unsigned)W) {
                        int ac = yy * W + xx;
                        if (ac >= a_lo && ac <= a_hi) {
                            if (is_hi) atomicOr(&s_ghi[ac - a_lo], bit);
                            else       atomicOr(&s_glo[ac - a_lo], bit);
                        }
                    }
                }
            }
        }
    }
    __syncthreads();

    // ---- Phase 2: per-anchor obj + box (R10 proven body) + class-union ----
    int ay;
    if (s == 0) ay = a / 52; else if (s == 1) ay = a / 26; else ay = a / 13;
    const int ax = a - ay * W;

    const unsigned glo = s_glo[tid], ghi = s_ghi[tid];
    const bool fg = (glo | ghi) != 0u;

    float obj_t = 0.f, box_t = 0.f, nfg = 0.f;
    if (active) {
        float xo = obj[(size_t)b * A + a];
        obj_t = bce_fast(xo, fg);
    }
    unsigned lo = 0u, hi = 0u;
    if (fg) {
        nfg = 1.0f;
        // class multi-hot = union of labels over covering GTs
        unsigned t = glo;
        while (t) {
            int m = __builtin_ctz(t); t &= t - 1;
            int lc = s_lab[m];
            if (lc < 32) lo |= 1u << lc; else hi |= 1u << (lc - 32);
        }
        t = ghi;
        while (t) {
            int m = 32 + __builtin_ctz(t); t &= t - 1;
            int lc = s_lab[m];
            if (lc < 32) lo |= 1u << lc; else hi |= 1u << (lc - 32);
        }
        // last-write-wins box target = max set GT index
        int mstar = ghi ? (32 + 31 - __builtin_clz(ghi)) : (31 - __builtin_clz(glo));
        float4 tb = s_boxv[mstar];

        // ---- box loss: decode + IoU with target ----
        const float* rp = reg + (size_t)b * 4 * A + a;
        float rx = rp[0], ry = rp[(size_t)A], rw = rp[(size_t)2 * A], rh = rp[(size_t)3 * A];
        float px = ((float)ax + rx) * strd;
        float py = ((float)ay + ry) * strd;
        rw = fminf(fmaxf(rw, -10.0f), 10.0f);
        rh = fminf(fmaxf(rh, -10.0f), 10.0f);
        float pw = __expf(rw) * strd;
        float ph = __expf(rh) * strd;
        float p0 = px - pw * 0.5f, p1 = py - ph * 0.5f;
        float p2 = px + pw * 0.5f, p3 = py + ph * 0.5f;
        float ix1 = fmaxf(p0, tb.x), iy1 = fmaxf(p1, tb.y);
        float ix2 = fminf(p2, tb.z), iy2 = fminf(p3, tb.w);
        float inter = fmaxf(ix2 - ix1, 0.0f) * fmaxf(iy2 - iy1, 0.0f);
        float pa = (p2 - p0) * (p3 - p1);
        float ta = (tb.z - tb.x) * (tb.w - tb.y);
        float iou = inter / (pa + ta - inter + 1e-7f);
        box_t = 1.0f - iou;
    }

    // Publish per-anchor class masks (each thread overwrites ITS OWN slot;
    // no cross-thread hazard, one barrier before the sweep reads them).
    s_glo[tid] = lo;   // ==0 for non-fg / inactive -> sweep contributes 0
    s_ghi[tid] = hi;
    __syncthreads();

    // ---- Phase 3: dense cls sweep. Wave w owns channels c = w + 4*cb.
    //      Non-tail: one aligned float4 load covers 4 anchors/lane (1KB/wave).
    float cls_t = 0.f;
    {
        const float* __restrict__ cbase = cls + (size_t)b * CC * A;
        const bool tail = (a_hi - a_lo) < 255;   // block-uniform
        const int au = a_lo + 4 * lane;
        const uint4 lo4 = *reinterpret_cast<const uint4*>(&s_glo[4 * lane]);
        const uint4 hi4 = *reinterpret_cast<const uint4*>(&s_ghi[4 * lane]);
        const bool f0 = (lo4.x | hi4.x) != 0u;
        const bool f1 = (lo4.y | hi4.y) != 0u;
        const bool f2 = (lo4.z | hi4.z) != 0u;
        const bool f3 = (lo4.w | hi4.w) != 0u;
        if (!tail) {
            #pragma unroll
            for (int cb = 0; cb < 11; ++cb) {
                const int c = wid + 4 * cb;       // wave-uniform channel
                if (c < CC) {
                    const float4 x = *reinterpret_cast<const float4*>(cbase + (size_t)c * A + au);
                    const bool b0 = ((c < 32) ? (lo4.x >> c) : (hi4.x >> (c - 32))) & 1u;
                    const bool b1 = ((c < 32) ? (lo4.y >> c) : (hi4.y >> (c - 32))) & 1u;
                    const bool b2 = ((c < 32) ? (lo4.z >> c) : (hi4.z >> (c - 32))) & 1u;
                    const bool b3 = ((c < 32) ? (lo4.w >> c) : (hi4.w >> (c - 32))) & 1u;
                    cls_t += f0 ? focal_fast(x.x, b0) : 0.f;
                    cls_t += f1 ? focal_fast(x.y, b1) : 0.f;
                    cls_t += f2 ? focal_fast(x.z, b2) : 0.f;
                    cls_t += f3 ? focal_fast(x.w, b3) : 0.f;
                }
            }
        } else {
            const int i0 = min(au + 0, A - 1), i1 = min(au + 1, A - 1);
            const int i2 = min(au + 2, A - 1), i3 = min(au + 3, A - 1);
            #pragma unroll
            for (int cb = 0; cb < 11; ++cb) {
                const int c = wid + 4 * cb;
                if (c < CC) {
                    const float* ch = cbase + (size_t)c * A;
                    const float x0 = ch[i0], x1 = ch[i1], x2 = ch[i2], x3 = ch[i3];
                    const bool b0 = ((c < 32) ? (lo4.x >> c) : (hi4.x >> (c - 32))) & 1u;
                    const bool b1 = ((c < 32) ? (lo4.y >> c) : (hi4.y >> (c - 32))) & 1u;
                    const bool b2 = ((c < 32) ? (lo4.z >> c) : (hi4.z >> (c - 32))) & 1u;
                    const bool b3 = ((c < 32) ? (lo4.w >> c) : (hi4.w >> (c - 32))) & 1u;
                    cls_t += f0 ? focal_fast(x0, b0) : 0.f;
                    cls_t += f1 ? focal_fast(x1, b1) : 0.f;
                    cls_t += f2 ? focal_fast(x2, b2) : 0.f;
                    cls_t += f3 ? focal_fast(x3, b3) : 0.f;
                }
            }
        }
    }

    // Deterministic block reduction: wave shfl_xor then LDS across 4 waves.
    for (int off = 32; off > 0; off >>= 1) {
        obj_t += __shfl_xor(obj_t, off);
        cls_t += __shfl_xor(cls_t, off);
        box_t += __shfl_xor(box_t, off);
        nfg   += __shfl_xor(nfg,   off);
    }
    __shared__ float s_red[4][4];
    if (lane == 0) {
        s_red[wid][0] = obj_t; s_red[wid][1] = cls_t;
        s_red[wid][2] = box_t; s_red[wid][3] = nfg;
    }
    __syncthreads();
    if (tid == 0) {
        float o = 0.f, c = 0.f, bx = 0.f, nf = 0.f;
        for (int w = 0; w < 4; ++w) {
            o += s_red[w][0]; c += s_red[w][1]; bx += s_red[w][2]; nf += s_red[w][3];
        }
        float* p = partials + (size_t)bid * 4;
        p[0] = o; p[1] = c; p[2] = bx; p[3] = nf;
    }
}

__global__ __launch_bounds__(256) void v3_final(const float* __restrict__ partials,
                                                float* __restrict__ out)
{
    const int tid = threadIdx.x;
    double o[3] = {0, 0, 0}, c[3] = {0, 0, 0}, bx[3] = {0, 0, 0}, nf[3] = {0, 0, 0};
    for (int i = tid; i < NBLK_TOTAL; i += 256) {
        int s = (i < NBLK0) ? 0 : ((i < NBLK01) ? 1 : 2);
        const float* p = partials + (size_t)i * 4;
        o[s]  += (double)p[0];
        c[s]  += (double)p[1];
        bx[s] += (double)p[2];
        nf[s] += (double)p[3];
    }
    for (int off = 32; off > 0; off >>= 1) {
        for (int s = 0; s < 3; ++s) {
            o[s]  += __shfl_xor(o[s],  off);
            c[s]  += __shfl_xor(c[s],  off);
            bx[s] += __shfl_xor(bx[s], off);
            nf[s] += __shfl_xor(nf[s], off);
        }
    }
    __shared__ double s_red[4][12];
    int wid = tid >> 6, lane = tid & 63;
    if (lane == 0) {
        for (int s = 0; s < 3; ++s) {
            s_red[wid][s * 4 + 0] = o[s];
            s_red[wid][s * 4 + 1] = c[s];
            s_red[wid][s * 4 + 2] = bx[s];
            s_red[wid][s * 4 + 3] = nf[s];
        }
    }
    __syncthreads();
    if (tid == 0) {
        double total = 0.0;
        for (int s = 0; s < 3; ++s) {
            double os = 0, cs = 0, bs = 0, ns = 0;
            for (int w = 0; w < 4; ++w) {
                os += s_red[w][s * 4 + 0];
                cs += s_red[w][s * 4 + 1];
                bs += s_red[w][s * 4 + 2];
                ns += s_red[w][s * 4 + 3];
            }
            double n = (ns > 1.0) ? ns : 1.0;
            total += 0.5 * (cs / (n * (double)CC)) + 7.5 * (bs / n) + 1.0 * (os / n);
        }
        out[0] = (float)(total / 3.0);
    }
}

extern "C" void kernel_launch(void* const* d_in, const int* in_sizes, int n_in,
                              void* d_out, int out_size, void* d_ws, size_t ws_size,
                              hipStream_t stream) {
    const float* cls0 = (const float*)d_in[0];
    const float* reg0 = (const float*)d_in[1];
    const float* obj0 = (const float*)d_in[2];
    const float* cls1 = (const float*)d_in[3];
    const float* reg1 = (const float*)d_in[4];
    const float* obj1 = (const float*)d_in[5];
    const float* cls2 = (const float*)d_in[6];
    const float* reg2 = (const float*)d_in[7];
    const float* obj2 = (const float*)d_in[8];
    const float* bboxes = (const float*)d_in[9];
    const int*   labels = (const int*)d_in[10];

    float* partials = (float*)d_ws;   // 1920*4 floats = 30720 B

    v3_main<<<NBLK_TOTAL, 256, 0, stream>>>(cls0, reg0, obj0, cls1, reg1, obj1,
                                            cls2, reg2, obj2, bboxes, labels,
                                            partials);
    v3_final<<<1, 256, 0, stream>>>(partials, (float*)d_out);
}

// Round 13
// 31.249 us; speedup vs baseline: 1.2209x; 1.2209x over previous
//
#include <hip/hip_runtime.h>
#include <math.h>

// Problem constants
#define BB 128
#define MM 50
#define CC 43
#define IMGF 416.0f

// Per-scale geometry:
//  s=0: W=52 A=2704 stride=8  chunks/b=11  blocks [0,1408)
//  s=1: W=26 A=676  stride=16 chunks/b=3   blocks [1408,1792)
//  s=2: W=13 A=169  stride=32 chunks/b=1   blocks [1792,1920)
#define NBLK0 1408
#define NBLK01 1792
#define NBLK_TOTAL 1920

// focal = alpha*(1-pt)^2 * bce, with bce = -log(pt), pt = t ? sig(x) : 1-sig(x).
// sig path: e = exp(-|x|), d = 1+e, r = 1/d; pt = (xp>=0) ? r : e*r with xp = t?x:-x.
__device__ __forceinline__ float focal_fast(float x, bool t) {
    float xp = t ? x : -x;
    float e = __expf(-fabsf(xp));          // v_exp
    float d = 1.0f + e;
    float r = __builtin_amdgcn_rcpf(d);    // v_rcp
    float pt = (xp >= 0.0f) ? r : e * r;
    float om = 1.0f - pt;
    float bce = -__logf(pt);               // v_log
    return 0.25f * om * om * bce;
}

__device__ __forceinline__ float bce_fast(float x, bool t) {
    float e = __expf(-fabsf(x));
    float l = __logf(1.0f + e);
    return fmaxf(x, 0.0f) - (t ? x : 0.0f) + l;
}

// SESSION RULES: (1) no agent-scope ordered atomics anywhere (R8/R9 A/B:
// 49->96us); final reduce stays a separate kernel. (2) R11: hoisting the 43
// cls gathers into registers regressed; R12: dense channel sweep regressed
// (4x focal overcompute). The R10 sparse shape is the proven fastest.
// R13 micro-opts only: obj/reg loads hoisted above the LDS phases (latency
// hides under prologue), cheaper focal (-log(pt)), launch_bounds occupancy.
__global__ __launch_bounds__(256, 8) void v3_main(
    const float* __restrict__ cls0, const float* __restrict__ reg0, const float* __restrict__ obj0,
    const float* __restrict__ cls1, const float* __restrict__ reg1, const float* __restrict__ obj1,
    const float* __restrict__ cls2, const float* __restrict__ reg2, const float* __restrict__ obj2,
    const float* __restrict__ bboxes, const int* __restrict__ labels,
    float* __restrict__ partials)
{
    const int bid = blockIdx.x;
    int s, b, chunk;
    if (bid < NBLK0)       { s = 0; b = bid / 11; chunk = bid - 11 * b; }
    else if (bid < NBLK01) { int r = bid - NBLK0; s = 1; b = r / 3; chunk = r - 3 * b; }
    else                   { s = 2; b = bid - NBLK01; chunk = 0; }

    int W, A; float strd, inv_strd;
    const float *cls, *reg, *obj;
    if (s == 0)      { W = 52; A = 2704; strd = 8.f;  inv_strd = 0.125f;   cls = cls0; reg = reg0; obj = obj0; }
    else if (s == 1) { W = 26; A = 676;  strd = 16.f; inv_strd = 0.0625f;  cls = cls1; reg = reg1; obj = obj1; }
    else             { W = 13; A = 169;  strd = 32.f; inv_strd = 0.03125f; cls = cls2; reg = reg2; obj = obj2; }

    const int tid = threadIdx.x;
    const int lane = tid & 63, wid = tid >> 6;
    const int a_lo = chunk << 8;
    const int a_hi = min(a_lo + 255, A - 1);
    const int a = a_lo + tid;
    const bool active = (a < A);
    const int ac = min(a, A - 1);   // clamped: safe unconditional addresses

    // ---- hoisted global loads: issued before any barrier so their latency
    //      overlaps the LDS prologue. obj needed by all; reg loaded densely
    //      (clamped) instead of fg-masked — extra bytes are L3-resident. ----
    const float xo = obj[(size_t)b * A + ac];
    const float* rp = reg + (size_t)b * 4 * A + ac;
    float rx = rp[0], ry = rp[(size_t)A], rw = rp[(size_t)2 * A], rh = rp[(size_t)3 * A];

    int   my_lab = -1;
    float4 my_bb;
    if (tid < MM) {
        my_lab = labels[b * MM + tid];
        my_bb  = ((const float4*)bboxes)[b * MM + tid];
    }

    // ---- LDS: GT staging + per-cell GT-incidence masks (block-local) ----
    __shared__ int    s_lab[MM];
    __shared__ float4 s_boxv[MM];
    __shared__ unsigned s_glo[256], s_ghi[256];

    // Phase 1a: zero cell masks; 50 lanes stage GT data + centers
    s_glo[tid] = 0u; s_ghi[tid] = 0u;
    int gx = -1, gy = -1;
    if (tid < MM) {
        float4 pb = make_float4(my_bb.x * IMGF, my_bb.y * IMGF, my_bb.z * IMGF, my_bb.w * IMGF);
        s_boxv[tid] = pb;
        s_lab[tid] = min(max(my_lab, 0), CC - 1);
        float cx = (pb.x + pb.z) * 0.5f;
        float cy = (pb.y + pb.w) * 0.5f;
        gx = (int)(cx * inv_strd); gx = min(max(gx, 0), W - 1);
        gy = (int)(cy * inv_strd); gy = min(max(gy, 0), W - 1);
    }
    __syncthreads();

    // Phase 1b: idempotent scatter of GT bits into this block's cell window
    if (tid < MM && my_lab >= 0) {
        unsigned bit = 1u << (tid & 31);
        bool is_hi = (tid >= 32);
        #pragma unroll
        for (int dy = -1; dy <= 1; ++dy) {
            int yy = gy + dy;
            if ((unsigned)yy < (unsigned)W) {
                #pragma unroll
                for (int dx = -1; dx <= 1; ++dx) {
                    int xx = gx + dx;
                    if ((unsigned)xx < (unsigned)W) {
                        int acell = yy * W + xx;
                        if (acell >= a_lo && acell <= a_hi) {
                            if (is_hi) atomicOr(&s_ghi[acell - a_lo], bit);
                            else       atomicOr(&s_glo[acell - a_lo], bit);
                        }
                    }
                }
            }
        }
    }
    __syncthreads();

    // ---- Phase 2: per-anchor losses (R10 proven body) ----
    int ay;
    if (s == 0) ay = a / 52; else if (s == 1) ay = a / 26; else ay = a / 13;
    const int ax = a - ay * W;

    const unsigned glo = s_glo[tid], ghi = s_ghi[tid];
    const bool fg = (glo | ghi) != 0u;   // inactive cells never receive bits

    float obj_t = 0.f, cls_t = 0.f, box_t = 0.f, nfg = 0.f;
    if (active) obj_t = bce_fast(xo, fg);

    if (fg) {
        nfg = 1.0f;
        // class multi-hot = union of labels over covering GTs
        unsigned lo = 0u, hi = 0u;
        unsigned t = glo;
        while (t) {
            int m = __builtin_ctz(t); t &= t - 1;
            int lc = s_lab[m];
            if (lc < 32) lo |= 1u << lc; else hi |= 1u << (lc - 32);
        }
        t = ghi;
        while (t) {
            int m = 32 + __builtin_ctz(t); t &= t - 1;
            int lc = s_lab[m];
            if (lc < 32) lo |= 1u << lc; else hi |= 1u << (lc - 32);
        }
        // last-write-wins box target = max set GT index
        int mstar = ghi ? (32 + 31 - __builtin_clz(ghi)) : (31 - __builtin_clz(glo));
        float4 tb = s_boxv[mstar];

        // ---- box loss: decode + IoU with target (reg values pre-loaded) ----
        float px = ((float)ax + rx) * strd;
        float py = ((float)ay + ry) * strd;
        rw = fminf(fmaxf(rw, -10.0f), 10.0f);
        rh = fminf(fmaxf(rh, -10.0f), 10.0f);
        float pw = __expf(rw) * strd;
        float ph = __expf(rh) * strd;
        float p0 = px - pw * 0.5f, p1 = py - ph * 0.5f;
        float p2 = px + pw * 0.5f, p3 = py + ph * 0.5f;
        float ix1 = fmaxf(p0, tb.x), iy1 = fmaxf(p1, tb.y);
        float ix2 = fminf(p2, tb.z), iy2 = fminf(p3, tb.w);
        float inter = fmaxf(ix2 - ix1, 0.0f) * fmaxf(iy2 - iy1, 0.0f);
        float pa = (p2 - p0) * (p3 - p1);
        float ta = (tb.z - tb.x) * (tb.w - tb.y);
        float iou = inter / (pa + ta - inter + 1e-7f);
        box_t = 1.0f - iou;

        // ---- cls focal loss over 43 channels (multi-hot target) ----
        const float* cp = cls + (size_t)b * CC * A + a;
        float acc = 0.0f;
        #pragma unroll
        for (int c = 0; c < CC; ++c) {
            float xv = cp[(size_t)c * A];
            bool bit = (c < 32) ? (((lo >> c) & 1u) != 0u) : (((hi >> (c - 32)) & 1u) != 0u);
            acc += focal_fast(xv, bit);
        }
        cls_t = acc;
    }

    // Deterministic block reduction: wave shfl_xor then LDS across 4 waves.
    for (int off = 32; off > 0; off >>= 1) {
        obj_t += __shfl_xor(obj_t, off);
        cls_t += __shfl_xor(cls_t, off);
        box_t += __shfl_xor(box_t, off);
        nfg   += __shfl_xor(nfg,   off);
    }
    __shared__ float s_red[4][4];
    if (lane == 0) {
        s_red[wid][0] = obj_t; s_red[wid][1] = cls_t;
        s_red[wid][2] = box_t; s_red[wid][3] = nfg;
    }
    __syncthreads();
    if (tid == 0) {
        float o = 0.f, c = 0.f, bx = 0.f, nf = 0.f;
        for (int w = 0; w < 4; ++w) {
            o += s_red[w][0]; c += s_red[w][1]; bx += s_red[w][2]; nf += s_red[w][3];
        }
        float* p = partials + (size_t)bid * 4;
        p[0] = o; p[1] = c; p[2] = bx; p[3] = nf;
    }
}

__global__ __launch_bounds__(256) void v3_final(const float* __restrict__ partials,
                                                float* __restrict__ out)
{
    const int tid = threadIdx.x;
    double o[3] = {0, 0, 0}, c[3] = {0, 0, 0}, bx[3] = {0, 0, 0}, nf[3] = {0, 0, 0};
    for (int i = tid; i < NBLK_TOTAL; i += 256) {
        int s = (i < NBLK0) ? 0 : ((i < NBLK01) ? 1 : 2);
        const float* p = partials + (size_t)i * 4;
        o[s]  += (double)p[0];
        c[s]  += (double)p[1];
        bx[s] += (double)p[2];
        nf[s] += (double)p[3];
    }
    for (int off = 32; off > 0; off >>= 1) {
        for (int s = 0; s < 3; ++s) {
            o[s]  += __shfl_xor(o[s],  off);
            c[s]  += __shfl_xor(c[s],  off);
            bx[s] += __shfl_xor(bx[s], off);
            nf[s] += __shfl_xor(nf[s], off);
        }
    }
    __shared__ double s_red[4][12];
    int wid = tid >> 6, lane = tid & 63;
    if (lane == 0) {
        for (int s = 0; s < 3; ++s) {
            s_red[wid][s * 4 + 0] = o[s];
            s_red[wid][s * 4 + 1] = c[s];
            s_red[wid][s * 4 + 2] = bx[s];
            s_red[wid][s * 4 + 3] = nf[s];
        }
    }
    __syncthreads();
    if (tid == 0) {
        double total = 0.0;
        for (int s = 0; s < 3; ++s) {
            double os = 0, cs = 0, bs = 0, ns = 0;
            for (int w = 0; w < 4; ++w) {
                os += s_red[w][s * 4 + 0];
                cs += s_red[w][s * 4 + 1];
                bs += s_red[w][s * 4 + 2];
                ns += s_red[w][s * 4 + 3];
            }
            double n = (ns > 1.0) ? ns : 1.0;
            total += 0.5 * (cs / (n * (double)CC)) + 7.5 * (bs / n) + 1.0 * (os / n);
        }
        out[0] = (float)(total / 3.0);
    }
}

extern "C" void kernel_launch(void* const* d_in, const int* in_sizes, int n_in,
                              void* d_out, int out_size, void* d_ws, size_t ws_size,
                              hipStream_t stream) {
    const float* cls0 = (const float*)d_in[0];
    const float* reg0 = (const float*)d_in[1];
    const float* obj0 = (const float*)d_in[2];
    const float* cls1 = (const float*)d_in[3];
    const float* reg1 = (const float*)d_in[4];
    const float* obj1 = (const float*)d_in[5];
    const float* cls2 = (const float*)d_in[6];
    const float* reg2 = (const float*)d_in[7];
    const float* obj2 = (const float*)d_in[8];
    const float* bboxes = (const float*)d_in[9];
    const int*   labels = (const int*)d_in[10];

    float* partials = (float*)d_ws;   // 1920*4 floats = 30720 B

    v3_main<<<NBLK_TOTAL, 256, 0, stream>>>(cls0, reg0, obj0, cls1, reg1, obj1,
                                            cls2, reg2, obj2, bboxes, labels,
                                            partials);
    v3_final<<<1, 256, 0, stream>>>(partials, (float*)d_out);
}